// Round 10
// baseline (230.331 us; speedup 1.0000x reference)
//
#include <hip/hip_runtime.h>

#define S_    2048
#define N_    16
#define OBS_  8
#define PRED_ 12
#define B_    (S_*N_)

typedef __attribute__((ext_vector_type(8))) short short8;
typedef __attribute__((ext_vector_type(4))) float floatx4;
typedef __attribute__((ext_vector_type(4))) unsigned uintx4;
typedef unsigned short ushort_t;

__device__ __forceinline__ float4 ld4(const float* p) { return *(const float4*)p; }
__device__ __forceinline__ float sigmf(float x) { return __builtin_amdgcn_rcpf(1.0f + __expf(-x)); }
__device__ __forceinline__ float tanhx(float x) { return fmaf(-2.0f, __builtin_amdgcn_rcpf(1.0f + __expf(2.0f*x)), 1.0f); }
// f32 -> bf16 round-half-up: bits+0x8000, truncate. <=0.5 ulp like RNE (ties differ only).
__device__ __forceinline__ unsigned bfhi(float f) {
  return __builtin_bit_cast(unsigned, f) + 0x8000u;
}
__device__ __forceinline__ unsigned pack2bf(float lo, float hi) {
  return __builtin_amdgcn_perm(bfhi(hi), bfhi(lo), 0x07060302);  // [hi.b3,hi.b2,lo.b3,lo.b2]
}
__device__ __forceinline__ ushort_t f2bf1(float f) { return (ushort_t)(bfhi(f) >> 16); }

__device__ __forceinline__ float dot16w(const float* w, const float4 x0, const float4 x1,
                                        const float4 x2, const float4 x3) {
  float4 w0 = ld4(w); float4 w1 = ld4(w+4); float4 w2 = ld4(w+8); float4 w3 = ld4(w+12);
  float a = x0.x*w0.x + x0.y*w0.y + x0.z*w0.z + x0.w*w0.w;
  float b = x1.x*w1.x + x1.y*w1.y + x1.z*w1.z + x1.w*w1.w;
  float c = x2.x*w2.x + x2.y*w2.y + x2.z*w2.z + x2.w*w2.w;
  float d = x3.x*w3.x + x3.y*w3.y + x3.z*w3.z + x3.w*w3.w;
  return (a+b)+(c+d);
}

// R10: TWO scenes per 512-thread block. Waves 0-3 = scene 0, waves 4-7 = scene 1;
// no cross-scene dataflow, per-thread register state unchanged. Rationale:
// OccupancyPercent pinned at ~38% (~3 blocks/CU) for R6-R9 regardless of LDS
// (22.5-41 KB), so the residency cap is per-BLOCK; 8-wave blocks double waves/CU
// to ~24 and halve global barrier events.
// SKELETON RULE (R2-R5 evidence): keep every barrier; change only phase bodies.
// Merging phases / removing barriers extends live ranges -> scratch spills ->
// 700-900 MB HBM traffic. Barriers are scheduling fences.
extern "C" __global__ __launch_bounds__(512, 6) void traj_ar_kernel(
    const float* __restrict__ traj_rel, const float* __restrict__ obs_pos,
    const int*  __restrict__ nei,       const float* __restrict__ noise,
    const float* __restrict__ eeW, const float* __restrict__ eeb,
    const float* __restrict__ eWi, const float* __restrict__ eWh, const float* __restrict__ eb,
    const float* __restrict__ diW, const float* __restrict__ dib,
    const float* __restrict__ dWi, const float* __restrict__ dWh, const float* __restrict__ db,
    const float* __restrict__ prW, const float* __restrict__ prb,
    const float* __restrict__ mW,  const float* __restrict__ mb,
    const float* __restrict__ oW,  const float* __restrict__ ob,
    float* __restrict__ out)
{
  // shared weights (one copy for both scenes)
  __shared__ __align__(16) float sW_diT[16*20];   // transposed, stride 20 (80B, 2-way alias free)
  __shared__ __align__(16) float sb_di[16];
  __shared__ __align__(16) float sW_pr[32];
  __shared__ __align__(16) float sb_pr[16];
  __shared__ __align__(16) float sW_o[64];
  __shared__ __align__(16) float sb_o[4];
  // per-scene state [sc][...]
  __shared__ __align__(16) float h_s[2][256];       // f32 h, phase-5 input
  __shared__ __align__(16) float ctx_s[2][256];
  // gate tiles: plane gt = 256 floats, [agent*16 + unit]; b128 writes at the
  // 8 words/bank floor; b32 reads at i*16+k are 2/bank = free.
  __shared__ __align__(16) float g_s[2][4*256];
  // bf16 activations, [agent][unit] stride 24 ushorts (48B, b128-aligned)
  __shared__ __align__(16) ushort_t e_bf[2][16*24];
  __shared__ __align__(16) ushort_t hb_s[2][16*24];
  // pool embeddings bf16: [i][j] j-stride 24 ushorts, i-stride 392 (784B)
  __shared__ __align__(16) ushort_t re_s[2][16*392];
  __shared__ __align__(16) float pos_s[2][32];
  __shared__ __align__(16) float prev_s[2][32];
  __shared__            unsigned sm_s[2][16];       // neighbor mask bits per agent

  const int tid = threadIdx.x;
  const int sc  = tid >> 8;             // scene half within block
  const int t8  = tid & 255;
  const int i = t8 >> 4;
  const int k = t8 & 15;
  const int s = blockIdx.x*2 + sc;
  const int bi = s*N_ + i;
  const int lq = (tid & 63) >> 4;       // quad within wave
  const int lc = tid & 15;              // col within wave (== k)
  const int w  = t8 >> 6;               // wave-within-scene == gate type (0..3)

  // ---- stage shared weights into LDS ----
  if (tid < 288) { int m = tid >> 4, c = tid & 15; sW_diT[c*20+m] = diW[tid]; }
  if (tid < 16) sb_di[tid] = dib[tid];
  if (tid < 32) sW_pr[tid] = prW[tid];
  if (tid < 16) sb_pr[tid] = prb[tid];
  if (tid < 64) sW_o[tid] = oW[tid];
  if (tid < 4)  sb_o[tid] = ob[tid];
  if (tid < 384) ((unsigned*)hb_s)[tid] = 0;   // h0 = 0, both scenes

  ((float*)ctx_s)[tid] = 0.0f;
  if (k < 2) {
    prev_s[sc][i*2+k] = traj_rel[((OBS_-1)*B_ + bi)*2 + k];  // out init = traj_rel[OBS-1]
    pos_s[sc][i*2+k]  = obs_pos[((OBS_-1)*B_ + bi)*2 + k];   // pos init = obs_traj_pos[-1]
  }

  // pool-MLP B-fragment (32x16 bf16 weights)
  short8 bfrag;
  {
    uintx4 bw;
    #pragma unroll
    for (int p = 0; p < 4; ++p)
      bw[p] = pack2bf(mW[(8*lq + 2*p)*16 + lc], mW[(8*lq + 2*p + 1)*16 + lc]);
    bfrag = __builtin_bit_cast(short8, bw);
  }
  const float bm = mb[lc];

  // encoder embed weights per thread (unit k)
  const float w0k = eeW[k], w1k = eeW[16+k], bek = eeb[k];

  // encoder gate A-fragment for THIS wave's gate type w (constant) + bias C.
  short8 gA; floatx4 gC;
  {
    const int row0 = (lq & 1) * 8;
    const float* gsrc = (lq & 2) ? eWh : eWi;
    uintx4 aw;
    #pragma unroll
    for (int p = 0; p < 4; ++p)
      aw[p] = pack2bf(gsrc[(row0+2*p)*64 + w*16 + lc], gsrc[(row0+2*p+1)*64 + w*16 + lc]);
    gA = __builtin_bit_cast(short8, aw);
    #pragma unroll
    for (int r = 0; r < 4; ++r) gC[r] = eb[w*16 + lq*4 + r];   // bias by D-row unit
  }

  // time-invariant neighbor mask -> per-agent bitmask in LDS (wave-local layout
  // identical to 256-thread version: lane = (i&3)*16 + k)
  unsigned long long bal = __ballot(nei[bi*N_ + k] > 0);
  if (k == 0) sm_s[sc][i] = (unsigned)((bal >> (16*(i & 3))) & 0xFFFFull);

  __syncthreads();

  // ---- encoder: 8 LSTM steps, 2 barriers/step ----
  float c_reg = 0.0f;
  const float2* xr2 = (const float2*)traj_rel;
  for (int t = 0; t < OBS_; ++t) {
    // P1e: e[i][k] = relu(x @ eeW + b), bf16 to LDS
    {
      float2 x = xr2[t*B_ + bi];
      float e = fmaxf(fmaf(x.y, w1k, fmaf(x.x, w0k, bek)), 0.0f);
      e_bf[sc][i*24 + k] = f2bf1(e);
    }
    __syncthreads(); // A: e_bf ready; prev step's hb_s writes drained
    // P2a: this wave's gate-type MFMA -> g_s (D row = unit lq*4+r, col = agent lc)
    {
      const ushort_t* bp = (lq < 2) ? &e_bf[sc][lc*24 + (lq&1)*8] : &hb_s[sc][lc*24 + (lq&1)*8];
      short8 bfr = *(const short8*)bp;
      floatx4 d = __builtin_amdgcn_mfma_f32_16x16x32_bf16(gA, bfr, gC, 0, 0, 0);
      *(floatx4*)&g_s[sc][w*256 + lc*16 + lq*4] = d;
    }
    __syncthreads(); // B: g_s ready; hb_s MFMA reads drained
    // P2b: distributed elementwise — thread (sc,i,k) owns its (agent,unit) pair
    {
      float gI = g_s[sc][0*256 + i*16 + k];
      float gF = g_s[sc][1*256 + i*16 + k];
      float gG = g_s[sc][2*256 + i*16 + k];
      float gO = g_s[sc][3*256 + i*16 + k];
      float ig = sigmf(gI), fg = sigmf(gF), gv = tanhx(gG), og = sigmf(gO);
      c_reg = fg*c_reg + ig*gv;
      float nh = og * tanhx(c_reg);
      hb_s[sc][i*24 + k] = f2bf1(nh);
    }
  }

  // decoder gate A-fragment + bias (loaded after encoder: separate live ranges)
  short8 dA; floatx4 dC;
  {
    const int row0 = (lq & 1) * 8;
    const float* gsrc = (lq & 2) ? dWh : dWi;
    uintx4 aw;
    #pragma unroll
    for (int p = 0; p < 4; ++p)
      aw[p] = pack2bf(gsrc[(row0+2*p)*64 + w*16 + lc], gsrc[(row0+2*p+1)*64 + w*16 + lc]);
    dA = __builtin_bit_cast(short8, aw);
    #pragma unroll
    for (int r = 0; r < 4; ++r) dC[r] = db[w*16 + lq*4 + r];
  }

  // pool C-operands with mask baked in (time-invariant): tile tt's C[r] =
  // mask(4w+tt, row lq*4+r) ? mb[lc] : -1e9  -> relu(max) handles masked & all-masked.
  floatx4 cm0, cm1, cm2, cm3;
  {
    #pragma unroll
    for (int tt = 0; tt < 4; ++tt) {
      const unsigned mi = sm_s[sc][4*w + tt];
      floatx4 cf;
      #pragma unroll
      for (int r = 0; r < 4; ++r)
        cf[r] = ((mi >> (lq*4 + r)) & 1u) ? bm : -1e9f;
      if (tt==0) cm0=cf; else if (tt==1) cm1=cf; else if (tt==2) cm2=cf; else cm3=cf;
    }
  }

  // ---- decoder: 12 autoregressive steps, 5 barriers/step ----
  c_reg = 0.0f;                       // decoder c starts at zero
  const int MU_OFF = PRED_*B_*2;
  const int SD_OFF = 2*PRED_*B_*2;
  for (int t = 0; t < PRED_; ++t) {
    // early noise load: consumed in phase 5, ~4 phases of latency hiding.
    const float nz = noise[(t*B_ + bi)*2 + (k & 1)];
    // phase 1: e = relu([ctx, prev] @ dec_in_W + b), bf16 to LDS
    {
      const float* cx = &ctx_s[sc][i*16];
      float4 c0 = ld4(cx), c1 = ld4(cx+4), c2 = ld4(cx+8), c3 = ld4(cx+12);
      float p0 = prev_s[sc][i*2+0], p1 = prev_s[sc][i*2+1];
      const float* wd = &sW_diT[k*20];
      float acc = sb_di[k] + dot16w(wd, c0,c1,c2,c3) + p0*wd[16] + p1*wd[17];
      e_bf[sc][i*24 + k] = f2bf1(fmaxf(acc, 0.0f));
    }
    __syncthreads(); // A
    // phase 2a: this wave's gate-type MFMA -> g_s
    {
      const ushort_t* bp = (lq < 2) ? &e_bf[sc][lc*24 + (lq&1)*8] : &hb_s[sc][lc*24 + (lq&1)*8];
      short8 bfr = *(const short8*)bp;
      floatx4 d = __builtin_amdgcn_mfma_f32_16x16x32_bf16(dA, bfr, dC, 0, 0, 0);
      *(floatx4*)&g_s[sc][w*256 + lc*16 + lq*4] = d;
    }
    __syncthreads(); // B: g_s ready; hb_s MFMA reads drained
    // phase 2b: distributed elementwise; write f32 h (phase 5) + bf16 h (pool/next gates)
    {
      float gI = g_s[sc][0*256 + i*16 + k];
      float gF = g_s[sc][1*256 + i*16 + k];
      float gG = g_s[sc][2*256 + i*16 + k];
      float gO = g_s[sc][3*256 + i*16 + k];
      float ig = sigmf(gI), fg = sigmf(gF), gv = tanhx(gG), og = sigmf(gO);
      c_reg = fg*c_reg + ig*gv;
      float nh = og * tanhx(c_reg);
      h_s[sc][i*16 + k] = nh;
      hb_s[sc][i*24 + k] = f2bf1(nh);
    }
    // phase 3: re[i][j=k][:] = relu(rel @ prW + b), bf16 packed -> two b128 stores
    {
      float rx = pos_s[sc][i*2+0] - pos_s[sc][k*2+0];
      float ry = pos_s[sc][i*2+1] - pos_s[sc][k*2+1];
      uintx4 v0, v1;
      #pragma unroll
      for (int m = 0; m < 4; ++m) {
        float a0 = fmaxf(fmaf(ry, sW_pr[16+2*m], fmaf(rx, sW_pr[2*m],   sb_pr[2*m])),   0.0f);
        float a1 = fmaxf(fmaf(ry, sW_pr[17+2*m], fmaf(rx, sW_pr[2*m+1], sb_pr[2*m+1])), 0.0f);
        float b0 = fmaxf(fmaf(ry, sW_pr[24+2*m], fmaf(rx, sW_pr[8+2*m], sb_pr[8+2*m])), 0.0f);
        float b1 = fmaxf(fmaf(ry, sW_pr[25+2*m], fmaf(rx, sW_pr[9+2*m], sb_pr[9+2*m])), 0.0f);
        v0[m] = pack2bf(a0, a1);
        v1[m] = pack2bf(b0, b1);
      }
      uintx4* rp = (uintx4*)&re_s[sc][i*392 + k*24];
      rp[0] = v0;
      rp[1] = v1;
    }
    __syncthreads(); // C: re_s + hb_s (from P2b) ready for pool
    // phase 4: masked max-pool via MFMA with mask-baked C; pooled = relu(max over 16 rows)
    {
      const ushort_t* hbp = &hb_s[sc][lc*24 + (lq-2)*8];
      #pragma unroll
      for (int tt = 0; tt < 4; ++tt) {
        const int it = 4*w + tt;
        const ushort_t* rep = &re_s[sc][it*392 + lc*24 + lq*8];
        const ushort_t* ap = (lq < 2) ? rep : hbp;
        short8 a = *(const short8*)ap;
        const floatx4 cm = (tt==0)?cm0:(tt==1)?cm1:(tt==2)?cm2:cm3;
        floatx4 d = __builtin_amdgcn_mfma_f32_16x16x32_bf16(a, bfrag, cm, 0, 0, 0);
        float pm = fmaxf(fmaxf(d[0], d[1]), fmaxf(d[2], d[3]));
        pm = fmaxf(pm, __shfl_xor(pm, 16, 64));
        pm = fmaxf(pm, __shfl_xor(pm, 32, 64));
        if (lq == tt) ctx_s[sc][it*16 + lc] = fmaxf(pm, 0.0f);  // quad tt owns tile tt
      }
    }
    __syncthreads(); // D
    // phase 5: o4 = (h+ctx)@out_W + b; mu/std/pred; write outputs; advance pos
    {
      float o4v = 0.0f;
      if (k < 4) {
        const float* hp = &h_s[sc][i*16];
        const float* cx = &ctx_s[sc][i*16];
        float acc = sb_o[k];
        #pragma unroll
        for (int m = 0; m < 16; ++m) acc = fmaf(hp[m]+cx[m], sW_o[m*4+k], acc);
        o4v = acc;
      }
      float sc4 = __shfl_down(o4v, 2, 64);   // lane k<2 grabs o4[2+k]
      if (k < 2) {
        float mu = o4v;
        float scale = fminf(fmaxf(sc4, -9.0f), 4.0f);
        float sd = __expf(scale);
        float pr = fmaf(sd, nz, mu);
        int o = (t*B_ + bi)*2 + k;
        out[o]          = pr;
        out[MU_OFF + o] = mu;
        out[SD_OFF + o] = sd;
        pos_s[sc][i*2+k] += pr;
        prev_s[sc][i*2+k] = pr;
      }
    }
    __syncthreads(); // E
  }
}

extern "C" void kernel_launch(void* const* d_in, const int* in_sizes, int n_in,
                              void* d_out, int out_size, void* d_ws, size_t ws_size,
                              hipStream_t stream) {
  (void)in_sizes; (void)n_in; (void)d_ws; (void)ws_size; (void)out_size;
  traj_ar_kernel<<<dim3(S_/2), dim3(512), 0, stream>>>(
      (const float*)d_in[0],  (const float*)d_in[1],  (const int*)d_in[2],   (const float*)d_in[3],
      (const float*)d_in[4],  (const float*)d_in[5],  (const float*)d_in[6], (const float*)d_in[7],
      (const float*)d_in[8],  (const float*)d_in[9],  (const float*)d_in[10],(const float*)d_in[11],
      (const float*)d_in[12], (const float*)d_in[13], (const float*)d_in[14],(const float*)d_in[15],
      (const float*)d_in[16], (const float*)d_in[17], (const float*)d_in[18],(const float*)d_in[19],
      (float*)d_out);
}

// Round 11
// 184.680 us; speedup vs baseline: 1.2472x; 1.2472x over previous
//
#include <hip/hip_runtime.h>

#define S_    2048
#define N_    16
#define OBS_  8
#define PRED_ 12
#define B_    (S_*N_)

typedef __attribute__((ext_vector_type(8))) short short8;
typedef __attribute__((ext_vector_type(4))) float floatx4;
typedef __attribute__((ext_vector_type(4))) unsigned uintx4;
typedef unsigned short ushort_t;

__device__ __forceinline__ float4 ld4(const float* p) { return *(const float4*)p; }
__device__ __forceinline__ float sigmf(float x) { return __builtin_amdgcn_rcpf(1.0f + __expf(-x)); }
__device__ __forceinline__ float tanhx(float x) { return fmaf(-2.0f, __builtin_amdgcn_rcpf(1.0f + __expf(2.0f*x)), 1.0f); }
// f32 -> bf16 round-half-up: bits+0x8000, truncate. <=0.5 ulp like RNE (ties differ only).
__device__ __forceinline__ unsigned bfhi(float f) {
  return __builtin_bit_cast(unsigned, f) + 0x8000u;
}
__device__ __forceinline__ unsigned pack2bf(float lo, float hi) {
  return __builtin_amdgcn_perm(bfhi(hi), bfhi(lo), 0x07060302);  // [hi.b3,hi.b2,lo.b3,lo.b2]
}
__device__ __forceinline__ ushort_t f2bf1(float f) { return (ushort_t)(bfhi(f) >> 16); }

__device__ __forceinline__ float dot16w(const float* w, const float4 x0, const float4 x1,
                                        const float4 x2, const float4 x3) {
  float4 w0 = ld4(w); float4 w1 = ld4(w+4); float4 w2 = ld4(w+8); float4 w3 = ld4(w+12);
  float a = x0.x*w0.x + x0.y*w0.y + x0.z*w0.z + x0.w*w0.w;
  float b = x1.x*w1.x + x1.y*w1.y + x1.z*w1.z + x1.w*w1.w;
  float c = x2.x*w2.x + x2.y*w2.y + x2.z*w2.z + x2.w*w2.w;
  float d = x3.x*w3.x + x3.y*w3.y + x3.z*w3.z + x3.w*w3.w;
  return (a+b)+(c+d);
}

// R11: R10's two-scene/512-thread block with the register budget FIXED.
// R10's __launch_bounds__(512,6) capped VGPRs at ~85 -> allocator squeezed to 40
// -> per-thread fragments (dA/bfrag/cm0-3, ~36 regs of persistent state) spilled
// to scratch: FETCH 3.8->26.8 MB, WRITE 9.2->50.2 MB, dur 95->147 us. (512,4)
// caps at 128 VGPR (2 blocks/CU target = the residency R10 actually achieved).
// SKELETON RULE (R2-R5 evidence): keep every barrier; change only phase bodies.
extern "C" __global__ __launch_bounds__(512, 4) void traj_ar_kernel(
    const float* __restrict__ traj_rel, const float* __restrict__ obs_pos,
    const int*  __restrict__ nei,       const float* __restrict__ noise,
    const float* __restrict__ eeW, const float* __restrict__ eeb,
    const float* __restrict__ eWi, const float* __restrict__ eWh, const float* __restrict__ eb,
    const float* __restrict__ diW, const float* __restrict__ dib,
    const float* __restrict__ dWi, const float* __restrict__ dWh, const float* __restrict__ db,
    const float* __restrict__ prW, const float* __restrict__ prb,
    const float* __restrict__ mW,  const float* __restrict__ mb,
    const float* __restrict__ oW,  const float* __restrict__ ob,
    float* __restrict__ out)
{
  // shared weights (one copy for both scenes)
  __shared__ __align__(16) float sW_diT[16*20];   // transposed, stride 20 (80B, 2-way alias free)
  __shared__ __align__(16) float sb_di[16];
  __shared__ __align__(16) float sW_pr[32];
  __shared__ __align__(16) float sb_pr[16];
  __shared__ __align__(16) float sW_o[64];
  __shared__ __align__(16) float sb_o[4];
  // per-scene state [sc][...]
  __shared__ __align__(16) float h_s[2][256];       // f32 h, phase-5 input
  __shared__ __align__(16) float ctx_s[2][256];
  // gate tiles: plane gt = 256 floats, [agent*16 + unit]; b128 writes at the
  // 8 words/bank floor; b32 reads at i*16+k are 2/bank = free.
  __shared__ __align__(16) float g_s[2][4*256];
  // bf16 activations, [agent][unit] stride 24 ushorts (48B, b128-aligned)
  __shared__ __align__(16) ushort_t e_bf[2][16*24];
  __shared__ __align__(16) ushort_t hb_s[2][16*24];
  // pool embeddings bf16: [i][j] j-stride 24 ushorts, i-stride 392 (784B)
  __shared__ __align__(16) ushort_t re_s[2][16*392];
  __shared__ __align__(16) float pos_s[2][32];
  __shared__ __align__(16) float prev_s[2][32];
  __shared__            unsigned sm_s[2][16];       // neighbor mask bits per agent

  const int tid = threadIdx.x;
  const int sc  = tid >> 8;             // scene half within block
  const int t8  = tid & 255;
  const int i = t8 >> 4;
  const int k = t8 & 15;
  const int s = blockIdx.x*2 + sc;
  const int bi = s*N_ + i;
  const int lq = (tid & 63) >> 4;       // quad within wave
  const int lc = tid & 15;              // col within wave (== k)
  const int w  = t8 >> 6;               // wave-within-scene == gate type (0..3)

  // ---- stage shared weights into LDS ----
  if (tid < 288) { int m = tid >> 4, c = tid & 15; sW_diT[c*20+m] = diW[tid]; }
  if (tid < 16) sb_di[tid] = dib[tid];
  if (tid < 32) sW_pr[tid] = prW[tid];
  if (tid < 16) sb_pr[tid] = prb[tid];
  if (tid < 64) sW_o[tid] = oW[tid];
  if (tid < 4)  sb_o[tid] = ob[tid];
  if (tid < 384) ((unsigned*)hb_s)[tid] = 0;   // h0 = 0, both scenes

  ((float*)ctx_s)[tid] = 0.0f;
  if (k < 2) {
    prev_s[sc][i*2+k] = traj_rel[((OBS_-1)*B_ + bi)*2 + k];  // out init = traj_rel[OBS-1]
    pos_s[sc][i*2+k]  = obs_pos[((OBS_-1)*B_ + bi)*2 + k];   // pos init = obs_traj_pos[-1]
  }

  // pool-MLP B-fragment (32x16 bf16 weights)
  short8 bfrag;
  {
    uintx4 bw;
    #pragma unroll
    for (int p = 0; p < 4; ++p)
      bw[p] = pack2bf(mW[(8*lq + 2*p)*16 + lc], mW[(8*lq + 2*p + 1)*16 + lc]);
    bfrag = __builtin_bit_cast(short8, bw);
  }
  const float bm = mb[lc];

  // encoder embed weights per thread (unit k)
  const float w0k = eeW[k], w1k = eeW[16+k], bek = eeb[k];

  // encoder gate A-fragment for THIS wave's gate type w (constant) + bias C.
  short8 gA; floatx4 gC;
  {
    const int row0 = (lq & 1) * 8;
    const float* gsrc = (lq & 2) ? eWh : eWi;
    uintx4 aw;
    #pragma unroll
    for (int p = 0; p < 4; ++p)
      aw[p] = pack2bf(gsrc[(row0+2*p)*64 + w*16 + lc], gsrc[(row0+2*p+1)*64 + w*16 + lc]);
    gA = __builtin_bit_cast(short8, aw);
    #pragma unroll
    for (int r = 0; r < 4; ++r) gC[r] = eb[w*16 + lq*4 + r];   // bias by D-row unit
  }

  // time-invariant neighbor mask -> per-agent bitmask in LDS (wave-local layout
  // identical to 256-thread version: lane = (i&3)*16 + k)
  unsigned long long bal = __ballot(nei[bi*N_ + k] > 0);
  if (k == 0) sm_s[sc][i] = (unsigned)((bal >> (16*(i & 3))) & 0xFFFFull);

  __syncthreads();

  // ---- encoder: 8 LSTM steps, 2 barriers/step ----
  float c_reg = 0.0f;
  const float2* xr2 = (const float2*)traj_rel;
  for (int t = 0; t < OBS_; ++t) {
    // P1e: e[i][k] = relu(x @ eeW + b), bf16 to LDS
    {
      float2 x = xr2[t*B_ + bi];
      float e = fmaxf(fmaf(x.y, w1k, fmaf(x.x, w0k, bek)), 0.0f);
      e_bf[sc][i*24 + k] = f2bf1(e);
    }
    __syncthreads(); // A: e_bf ready; prev step's hb_s writes drained
    // P2a: this wave's gate-type MFMA -> g_s (D row = unit lq*4+r, col = agent lc)
    {
      const ushort_t* bp = (lq < 2) ? &e_bf[sc][lc*24 + (lq&1)*8] : &hb_s[sc][lc*24 + (lq&1)*8];
      short8 bfr = *(const short8*)bp;
      floatx4 d = __builtin_amdgcn_mfma_f32_16x16x32_bf16(gA, bfr, gC, 0, 0, 0);
      *(floatx4*)&g_s[sc][w*256 + lc*16 + lq*4] = d;
    }
    __syncthreads(); // B: g_s ready; hb_s MFMA reads drained
    // P2b: distributed elementwise — thread (sc,i,k) owns its (agent,unit) pair
    {
      float gI = g_s[sc][0*256 + i*16 + k];
      float gF = g_s[sc][1*256 + i*16 + k];
      float gG = g_s[sc][2*256 + i*16 + k];
      float gO = g_s[sc][3*256 + i*16 + k];
      float ig = sigmf(gI), fg = sigmf(gF), gv = tanhx(gG), og = sigmf(gO);
      c_reg = fg*c_reg + ig*gv;
      float nh = og * tanhx(c_reg);
      hb_s[sc][i*24 + k] = f2bf1(nh);
    }
  }

  // decoder gate A-fragment + bias (loaded after encoder: separate live ranges)
  short8 dA; floatx4 dC;
  {
    const int row0 = (lq & 1) * 8;
    const float* gsrc = (lq & 2) ? dWh : dWi;
    uintx4 aw;
    #pragma unroll
    for (int p = 0; p < 4; ++p)
      aw[p] = pack2bf(gsrc[(row0+2*p)*64 + w*16 + lc], gsrc[(row0+2*p+1)*64 + w*16 + lc]);
    dA = __builtin_bit_cast(short8, aw);
    #pragma unroll
    for (int r = 0; r < 4; ++r) dC[r] = db[w*16 + lq*4 + r];
  }

  // pool C-operands with mask baked in (time-invariant): tile tt's C[r] =
  // mask(4w+tt, row lq*4+r) ? mb[lc] : -1e9  -> relu(max) handles masked & all-masked.
  floatx4 cm0, cm1, cm2, cm3;
  {
    #pragma unroll
    for (int tt = 0; tt < 4; ++tt) {
      const unsigned mi = sm_s[sc][4*w + tt];
      floatx4 cf;
      #pragma unroll
      for (int r = 0; r < 4; ++r)
        cf[r] = ((mi >> (lq*4 + r)) & 1u) ? bm : -1e9f;
      if (tt==0) cm0=cf; else if (tt==1) cm1=cf; else if (tt==2) cm2=cf; else cm3=cf;
    }
  }

  // ---- decoder: 12 autoregressive steps, 5 barriers/step ----
  c_reg = 0.0f;                       // decoder c starts at zero
  const int MU_OFF = PRED_*B_*2;
  const int SD_OFF = 2*PRED_*B_*2;
  for (int t = 0; t < PRED_; ++t) {
    // early noise load: consumed in phase 5, ~4 phases of latency hiding.
    const float nz = noise[(t*B_ + bi)*2 + (k & 1)];
    // phase 1: e = relu([ctx, prev] @ dec_in_W + b), bf16 to LDS
    {
      const float* cx = &ctx_s[sc][i*16];
      float4 c0 = ld4(cx), c1 = ld4(cx+4), c2 = ld4(cx+8), c3 = ld4(cx+12);
      float p0 = prev_s[sc][i*2+0], p1 = prev_s[sc][i*2+1];
      const float* wd = &sW_diT[k*20];
      float acc = sb_di[k] + dot16w(wd, c0,c1,c2,c3) + p0*wd[16] + p1*wd[17];
      e_bf[sc][i*24 + k] = f2bf1(fmaxf(acc, 0.0f));
    }
    __syncthreads(); // A
    // phase 2a: this wave's gate-type MFMA -> g_s
    {
      const ushort_t* bp = (lq < 2) ? &e_bf[sc][lc*24 + (lq&1)*8] : &hb_s[sc][lc*24 + (lq&1)*8];
      short8 bfr = *(const short8*)bp;
      floatx4 d = __builtin_amdgcn_mfma_f32_16x16x32_bf16(dA, bfr, dC, 0, 0, 0);
      *(floatx4*)&g_s[sc][w*256 + lc*16 + lq*4] = d;
    }
    __syncthreads(); // B: g_s ready; hb_s MFMA reads drained
    // phase 2b: distributed elementwise; write f32 h (phase 5) + bf16 h (pool/next gates)
    {
      float gI = g_s[sc][0*256 + i*16 + k];
      float gF = g_s[sc][1*256 + i*16 + k];
      float gG = g_s[sc][2*256 + i*16 + k];
      float gO = g_s[sc][3*256 + i*16 + k];
      float ig = sigmf(gI), fg = sigmf(gF), gv = tanhx(gG), og = sigmf(gO);
      c_reg = fg*c_reg + ig*gv;
      float nh = og * tanhx(c_reg);
      h_s[sc][i*16 + k] = nh;
      hb_s[sc][i*24 + k] = f2bf1(nh);
    }
    // phase 3: re[i][j=k][:] = relu(rel @ prW + b), bf16 packed -> two b128 stores
    {
      float rx = pos_s[sc][i*2+0] - pos_s[sc][k*2+0];
      float ry = pos_s[sc][i*2+1] - pos_s[sc][k*2+1];
      uintx4 v0, v1;
      #pragma unroll
      for (int m = 0; m < 4; ++m) {
        float a0 = fmaxf(fmaf(ry, sW_pr[16+2*m], fmaf(rx, sW_pr[2*m],   sb_pr[2*m])),   0.0f);
        float a1 = fmaxf(fmaf(ry, sW_pr[17+2*m], fmaf(rx, sW_pr[2*m+1], sb_pr[2*m+1])), 0.0f);
        float b0 = fmaxf(fmaf(ry, sW_pr[24+2*m], fmaf(rx, sW_pr[8+2*m], sb_pr[8+2*m])), 0.0f);
        float b1 = fmaxf(fmaf(ry, sW_pr[25+2*m], fmaf(rx, sW_pr[9+2*m], sb_pr[9+2*m])), 0.0f);
        v0[m] = pack2bf(a0, a1);
        v1[m] = pack2bf(b0, b1);
      }
      uintx4* rp = (uintx4*)&re_s[sc][i*392 + k*24];
      rp[0] = v0;
      rp[1] = v1;
    }
    __syncthreads(); // C: re_s + hb_s (from P2b) ready for pool
    // phase 4: masked max-pool via MFMA with mask-baked C; pooled = relu(max over 16 rows)
    {
      const ushort_t* hbp = &hb_s[sc][lc*24 + (lq-2)*8];
      #pragma unroll
      for (int tt = 0; tt < 4; ++tt) {
        const int it = 4*w + tt;
        const ushort_t* rep = &re_s[sc][it*392 + lc*24 + lq*8];
        const ushort_t* ap = (lq < 2) ? rep : hbp;
        short8 a = *(const short8*)ap;
        const floatx4 cm = (tt==0)?cm0:(tt==1)?cm1:(tt==2)?cm2:cm3;
        floatx4 d = __builtin_amdgcn_mfma_f32_16x16x32_bf16(a, bfrag, cm, 0, 0, 0);
        float pm = fmaxf(fmaxf(d[0], d[1]), fmaxf(d[2], d[3]));
        pm = fmaxf(pm, __shfl_xor(pm, 16, 64));
        pm = fmaxf(pm, __shfl_xor(pm, 32, 64));
        if (lq == tt) ctx_s[sc][it*16 + lc] = fmaxf(pm, 0.0f);  // quad tt owns tile tt
      }
    }
    __syncthreads(); // D
    // phase 5: o4 = (h+ctx)@out_W + b; mu/std/pred; write outputs; advance pos
    {
      float o4v = 0.0f;
      if (k < 4) {
        const float* hp = &h_s[sc][i*16];
        const float* cx = &ctx_s[sc][i*16];
        float acc = sb_o[k];
        #pragma unroll
        for (int m = 0; m < 16; ++m) acc = fmaf(hp[m]+cx[m], sW_o[m*4+k], acc);
        o4v = acc;
      }
      float sc4 = __shfl_down(o4v, 2, 64);   // lane k<2 grabs o4[2+k]
      if (k < 2) {
        float mu = o4v;
        float scale = fminf(fmaxf(sc4, -9.0f), 4.0f);
        float sd = __expf(scale);
        float pr = fmaf(sd, nz, mu);
        int o = (t*B_ + bi)*2 + k;
        out[o]          = pr;
        out[MU_OFF + o] = mu;
        out[SD_OFF + o] = sd;
        pos_s[sc][i*2+k] += pr;
        prev_s[sc][i*2+k] = pr;
      }
    }
    __syncthreads(); // E
  }
}

extern "C" void kernel_launch(void* const* d_in, const int* in_sizes, int n_in,
                              void* d_out, int out_size, void* d_ws, size_t ws_size,
                              hipStream_t stream) {
  (void)in_sizes; (void)n_in; (void)d_ws; (void)ws_size; (void)out_size;
  traj_ar_kernel<<<dim3(S_/2), dim3(512), 0, stream>>>(
      (const float*)d_in[0],  (const float*)d_in[1],  (const int*)d_in[2],   (const float*)d_in[3],
      (const float*)d_in[4],  (const float*)d_in[5],  (const float*)d_in[6], (const float*)d_in[7],
      (const float*)d_in[8],  (const float*)d_in[9],  (const float*)d_in[10],(const float*)d_in[11],
      (const float*)d_in[12], (const float*)d_in[13], (const float*)d_in[14],(const float*)d_in[15],
      (const float*)d_in[16], (const float*)d_in[17], (const float*)d_in[18],(const float*)d_in[19],
      (float*)d_out);
}

// Round 13
// 177.569 us; speedup vs baseline: 1.2971x; 1.0401x over previous
//
#include <hip/hip_runtime.h>

#define S_    2048
#define N_    16
#define OBS_  8
#define PRED_ 12
#define B_    (S_*N_)

typedef __attribute__((ext_vector_type(8))) short short8;
typedef __attribute__((ext_vector_type(4))) float floatx4;
typedef __attribute__((ext_vector_type(4))) unsigned uintx4;
typedef unsigned short ushort_t;

__device__ __forceinline__ float sigmf(float x) { return __builtin_amdgcn_rcpf(1.0f + __expf(-x)); }
__device__ __forceinline__ float tanhx(float x) { return fmaf(-2.0f, __builtin_amdgcn_rcpf(1.0f + __expf(2.0f*x)), 1.0f); }
// f32 -> bf16 round-half-up: bits+0x8000, truncate. <=0.5 ulp like RNE (ties differ only).
__device__ __forceinline__ unsigned bfhi(float f) {
  return __builtin_bit_cast(unsigned, f) + 0x8000u;
}
__device__ __forceinline__ unsigned pack2bf(float lo, float hi) {
  return __builtin_amdgcn_perm(bfhi(hi), bfhi(lo), 0x07060302);  // [hi.b3,hi.b2,lo.b3,lo.b2]
}
__device__ __forceinline__ ushort_t f2bf1(float f) { return (ushort_t)(bfhi(f) >> 16); }

// one scene per block; thread (i = agent, k = hidden unit), 256 threads.
// R11 evidence: two-scene/512-thread blocks do NOT raise residency (~12-13
// waves/CU plateau regardless of block shape/LDS) and cost 6% -> 256 threads.
// SKELETON RULE (R2-R5 evidence): keep barriers; change phase bodies. Exception
// R12/R13: barrier D removed with a wave-locality proof (ctx_s/h_s writes and
// reads are same-wave, in-order LDS pipe; cross-wave ctx/prev consumers moved to
// bf16 side-buffers covered by barrier E). Spill tripwire: FETCH/WRITE ~3.9/9.2 MB.
// R13 = R12 + fix: ctx_bf zero-init covered only 96/192 uints (agents 8-15 read
// garbage ctx at t=0 -> absmax 1.3). hb_s-style `tid < 192` is correct.
extern "C" __global__ __launch_bounds__(256, 4) void traj_ar_kernel(
    const float* __restrict__ traj_rel, const float* __restrict__ obs_pos,
    const int*  __restrict__ nei,       const float* __restrict__ noise,
    const float* __restrict__ eeW, const float* __restrict__ eeb,
    const float* __restrict__ eWi, const float* __restrict__ eWh, const float* __restrict__ eb,
    const float* __restrict__ diW, const float* __restrict__ dib,
    const float* __restrict__ dWi, const float* __restrict__ dWh, const float* __restrict__ db,
    const float* __restrict__ prW, const float* __restrict__ prb,
    const float* __restrict__ mW,  const float* __restrict__ mb,
    const float* __restrict__ oW,  const float* __restrict__ ob,
    float* __restrict__ out)
{
  __shared__ __align__(16) float sW_pr[32];
  __shared__ __align__(16) float sb_pr[16];
  __shared__ __align__(16) float sW_o[64];
  __shared__ __align__(16) float sb_o[4];
  // state
  __shared__ __align__(16) float h_s[256];        // f32 h, phase-5 input
  __shared__ __align__(16) float ctx_s[256];      // f32 ctx, phase-5 input
  // gate tiles: plane gt = 256 floats, [agent*16 + unit]; b128 writes at the
  // 8 words/bank floor; b32 reads at i*16+k are 2/bank = free.
  __shared__ __align__(16) float g_s[4*256];
  // bf16 activations, [agent][unit] stride 24 ushorts (48B, b128-aligned)
  __shared__ __align__(16) ushort_t e_bf[16*24];
  __shared__ __align__(16) ushort_t hb_s[16*24];
  __shared__ __align__(16) ushort_t ctx_bf[16*24];  // bf16 ctx, phase-1 B input
  // pool embeddings bf16: [i][j] j-stride 24 ushorts, i-stride 392 (784B)
  __shared__ __align__(16) ushort_t re_s[16*392];
  __shared__ __align__(16) float pos_s[32];
  __shared__ __align__(16) float prev_s[32];
  __shared__ __align__(16) ushort_t prev_bf[32];    // bf16 prev, phase-1 B input
  __shared__            unsigned sm_s[16];   // neighbor mask bits per agent

  const int tid = threadIdx.x;
  const int s = blockIdx.x;
  const int i = tid >> 4;
  const int k = tid & 15;
  const int bi = s*N_ + i;
  const int lq = (tid & 63) >> 4;       // quad within wave
  const int lc = tid & 15;              // col within wave (== k)
  const int w  = tid >> 6;              // wave index == this wave's gate type

  // ---- stage small weights into LDS ----
  if (tid < 32) sW_pr[tid] = prW[tid];
  if (tid < 16) sb_pr[tid] = prb[tid];
  if (tid < 64) sW_o[tid] = oW[tid];
  if (tid < 4)  sb_o[tid] = ob[tid];
  if (tid < 192) ((unsigned*)hb_s)[tid] = 0;    // h0 = 0 for first encoder step
  if (tid < 192) ((unsigned*)ctx_bf)[tid] = 0;  // ctx0 = 0 for first decoder step (FULL 192 uints)

  if (k < 2) {
    float pv = traj_rel[((OBS_-1)*B_ + bi)*2 + k];
    prev_s[i*2+k] = pv;                  // out init = traj_rel[OBS-1]
    prev_bf[i*2+k] = f2bf1(pv);
    pos_s[i*2+k]  = obs_pos[((OBS_-1)*B_ + bi)*2 + k];   // pos init = obs_traj_pos[-1]
  }

  // pool-MLP B-fragment (32x16 bf16 weights)
  short8 bfrag;
  {
    uintx4 bw;
    #pragma unroll
    for (int p = 0; p < 4; ++p)
      bw[p] = pack2bf(mW[(8*lq + 2*p)*16 + lc], mW[(8*lq + 2*p + 1)*16 + lc]);
    bfrag = __builtin_bit_cast(short8, bw);
  }
  const float bm = mb[lc];

  // encoder embed weights per thread (unit k)
  const float w0k = eeW[k], w1k = eeW[16+k], bek = eeb[k];

  // encoder gate A-fragment for THIS wave's gate type w (constant) + bias C.
  short8 gA; floatx4 gC;
  {
    const int row0 = (lq & 1) * 8;
    const float* gsrc = (lq & 2) ? eWh : eWi;
    uintx4 aw;
    #pragma unroll
    for (int p = 0; p < 4; ++p)
      aw[p] = pack2bf(gsrc[(row0+2*p)*64 + w*16 + lc], gsrc[(row0+2*p+1)*64 + w*16 + lc]);
    gA = __builtin_bit_cast(short8, aw);
    #pragma unroll
    for (int r = 0; r < 4; ++r) gC[r] = eb[w*16 + lq*4 + r];   // bias by D-row unit
  }

  // time-invariant neighbor mask -> per-agent bitmask in LDS
  unsigned long long bal = __ballot(nei[bi*N_ + k] > 0);
  if (k == 0) sm_s[i] = (unsigned)((bal >> (16*(i & 3))) & 0xFFFFull);

  __syncthreads();

  // ---- encoder: 8 LSTM steps, 2 barriers/step ----
  float c_reg = 0.0f;
  const float2* xr2 = (const float2*)traj_rel;
  for (int t = 0; t < OBS_; ++t) {
    // P1e: e[i][k] = relu(x @ eeW + b), bf16 to LDS
    {
      float2 x = xr2[t*B_ + bi];
      float e = fmaxf(fmaf(x.y, w1k, fmaf(x.x, w0k, bek)), 0.0f);
      e_bf[i*24 + k] = f2bf1(e);
    }
    __syncthreads(); // A: e_bf ready; prev step's hb_s writes drained
    // P2a: this wave's gate-type MFMA -> g_s (D row = unit lq*4+r, col = agent lc)
    {
      const ushort_t* bp = (lq < 2) ? &e_bf[lc*24 + (lq&1)*8] : &hb_s[lc*24 + (lq&1)*8];
      short8 bfr = *(const short8*)bp;
      floatx4 d = __builtin_amdgcn_mfma_f32_16x16x32_bf16(gA, bfr, gC, 0, 0, 0);
      *(floatx4*)&g_s[w*256 + lc*16 + lq*4] = d;
    }
    __syncthreads(); // B: g_s ready; hb_s MFMA reads drained
    // P2b: distributed elementwise — thread (i,k) owns its (agent,unit) pair
    {
      float gI = g_s[0*256 + i*16 + k];
      float gF = g_s[1*256 + i*16 + k];
      float gG = g_s[2*256 + i*16 + k];
      float gO = g_s[3*256 + i*16 + k];
      float ig = sigmf(gI), fg = sigmf(gF), gv = tanhx(gG), og = sigmf(gO);
      c_reg = fg*c_reg + ig*gv;
      float nh = og * tanhx(c_reg);
      hb_s[i*24 + k] = f2bf1(nh);
    }
  }

  // decoder gate A-fragment + bias (loaded after encoder: separate live ranges)
  short8 dA; floatx4 dC;
  {
    const int row0 = (lq & 1) * 8;
    const float* gsrc = (lq & 2) ? dWh : dWi;
    uintx4 aw;
    #pragma unroll
    for (int p = 0; p < 4; ++p)
      aw[p] = pack2bf(gsrc[(row0+2*p)*64 + w*16 + lc], gsrc[(row0+2*p+1)*64 + w*16 + lc]);
    dA = __builtin_bit_cast(short8, aw);
    #pragma unroll
    for (int r = 0; r < 4; ++r) dC[r] = db[w*16 + lq*4 + r];
  }

  // dec-in A-fragment: A[m=lc][kk=lq*8+j] = diW[kk][lc], kk 0..15 = ctx rows,
  // kk 16,17 = prev rows, kk 18..31 zero-pad. Bias C by D-row unit.
  short8 diA; floatx4 diC;
  {
    uintx4 aw; aw[0]=0; aw[1]=0; aw[2]=0; aw[3]=0;
    if (lq < 2) {
      const int r0 = lq*8;
      #pragma unroll
      for (int p = 0; p < 4; ++p)
        aw[p] = pack2bf(diW[(r0+2*p)*16 + lc], diW[(r0+2*p+1)*16 + lc]);
    } else if (lq == 2) {
      aw[0] = pack2bf(diW[16*16 + lc], diW[17*16 + lc]);
    }
    diA = __builtin_bit_cast(short8, aw);
    #pragma unroll
    for (int r = 0; r < 4; ++r) diC[r] = dib[lq*4 + r];
  }

  // pool C-operands with mask baked in (time-invariant): tile tt's C[r] =
  // mask(4w+tt, row lq*4+r) ? mb[lc] : -1e9  -> relu(max) handles masked & all-masked.
  floatx4 cm0, cm1, cm2, cm3;
  {
    #pragma unroll
    for (int tt = 0; tt < 4; ++tt) {
      const unsigned mi = sm_s[4*w + tt];
      floatx4 cf;
      #pragma unroll
      for (int r = 0; r < 4; ++r)
        cf[r] = ((mi >> (lq*4 + r)) & 1u) ? bm : -1e9f;
      if (tt==0) cm0=cf; else if (tt==1) cm1=cf; else if (tt==2) cm2=cf; else cm3=cf;
    }
  }

  // ---- decoder: 12 autoregressive steps, 4 barriers/step ----
  c_reg = 0.0f;                       // decoder c starts at zero
  const int MU_OFF = PRED_*B_*2;
  const int SD_OFF = 2*PRED_*B_*2;
  for (int t = 0; t < PRED_; ++t) {
    // early noise load: consumed in phase 5, ~4 phases of latency hiding.
    const float nz = noise[(t*B_ + bi)*2 + (k & 1)];
    // phase 1 via MFMA: e = relu([ctx|prev] @ dec_in_W + b).
    // B[kk][agent=lc]: lq0/1 -> ctx_bf row lc; lq2 -> prev_bf pair + zeros; lq3 -> zeros.
    // All waves compute (uniform); wave 0 writes e_bf; barrier A covers readers.
    {
      short8 cv = *(const short8*)&ctx_bf[lc*24 + (lq&1)*8];
      uintx4 pz; pz[0] = *(const unsigned*)&prev_bf[lc*2]; pz[1]=0; pz[2]=0; pz[3]=0;
      short8 pv = __builtin_bit_cast(short8, pz);
      short8 zz = {0,0,0,0,0,0,0,0};
      short8 bfr = (lq < 2) ? cv : ((lq == 2) ? pv : zz);
      floatx4 d = __builtin_amdgcn_mfma_f32_16x16x32_bf16(diA, bfr, diC, 0, 0, 0);
      if (w == 0) {
        uint2 ep;
        ep.x = pack2bf(fmaxf(d[0],0.0f), fmaxf(d[1],0.0f));
        ep.y = pack2bf(fmaxf(d[2],0.0f), fmaxf(d[3],0.0f));
        *(uint2*)&e_bf[lc*24 + lq*4] = ep;   // e[agent lc][units lq*4..+3]
      }
    }
    __syncthreads(); // A: e_bf ready
    // phase 2a: this wave's gate-type MFMA -> g_s
    {
      const ushort_t* bp = (lq < 2) ? &e_bf[lc*24 + (lq&1)*8] : &hb_s[lc*24 + (lq&1)*8];
      short8 bfr = *(const short8*)bp;
      floatx4 d = __builtin_amdgcn_mfma_f32_16x16x32_bf16(dA, bfr, dC, 0, 0, 0);
      *(floatx4*)&g_s[w*256 + lc*16 + lq*4] = d;
    }
    __syncthreads(); // B: g_s ready; hb_s MFMA reads drained
    // phase 2b: distributed elementwise; write f32 h (phase 5) + bf16 h (pool/next gates)
    {
      float gI = g_s[0*256 + i*16 + k];
      float gF = g_s[1*256 + i*16 + k];
      float gG = g_s[2*256 + i*16 + k];
      float gO = g_s[3*256 + i*16 + k];
      float ig = sigmf(gI), fg = sigmf(gF), gv = tanhx(gG), og = sigmf(gO);
      c_reg = fg*c_reg + ig*gv;
      float nh = og * tanhx(c_reg);
      h_s[i*16 + k] = nh;
      hb_s[i*24 + k] = f2bf1(nh);
    }
    // phase 3: re[i][j=k][:] = relu(rel @ prW + b), bf16 packed -> two b128 stores
    {
      float rx = pos_s[i*2+0] - pos_s[k*2+0];
      float ry = pos_s[i*2+1] - pos_s[k*2+1];
      uintx4 v0, v1;
      #pragma unroll
      for (int m = 0; m < 4; ++m) {
        float a0 = fmaxf(fmaf(ry, sW_pr[16+2*m], fmaf(rx, sW_pr[2*m],   sb_pr[2*m])),   0.0f);
        float a1 = fmaxf(fmaf(ry, sW_pr[17+2*m], fmaf(rx, sW_pr[2*m+1], sb_pr[2*m+1])), 0.0f);
        float b0 = fmaxf(fmaf(ry, sW_pr[24+2*m], fmaf(rx, sW_pr[8+2*m], sb_pr[8+2*m])), 0.0f);
        float b1 = fmaxf(fmaf(ry, sW_pr[25+2*m], fmaf(rx, sW_pr[9+2*m], sb_pr[9+2*m])), 0.0f);
        v0[m] = pack2bf(a0, a1);
        v1[m] = pack2bf(b0, b1);
      }
      uintx4* rp = (uintx4*)&re_s[i*392 + k*24];
      rp[0] = v0;
      rp[1] = v1;
    }
    __syncthreads(); // C: re_s + hb_s (from P2b) ready for pool
    // phase 4: masked max-pool via MFMA with mask-baked C; pooled = relu(max over 16 rows).
    // Writes ctx f32 (phase 5, same wave) + ctx bf16 (phase 1 next step, barrier E).
    {
      const ushort_t* hbp = &hb_s[lc*24 + (lq-2)*8];
      #pragma unroll
      for (int tt = 0; tt < 4; ++tt) {
        const int it = 4*w + tt;
        const ushort_t* rep = &re_s[it*392 + lc*24 + lq*8];
        const ushort_t* ap = (lq < 2) ? rep : hbp;
        short8 a = *(const short8*)ap;
        const floatx4 cm = (tt==0)?cm0:(tt==1)?cm1:(tt==2)?cm2:cm3;
        floatx4 d = __builtin_amdgcn_mfma_f32_16x16x32_bf16(a, bfrag, cm, 0, 0, 0);
        float pm = fmaxf(fmaxf(d[0], d[1]), fmaxf(d[2], d[3]));
        pm = fmaxf(pm, __shfl_xor(pm, 16, 64));
        pm = fmaxf(pm, __shfl_xor(pm, 32, 64));
        if (lq == tt) {
          float cv = fmaxf(pm, 0.0f);
          ctx_s[it*16 + lc] = cv;            // same-wave consumer (phase 5)
          ctx_bf[it*24 + lc] = f2bf1(cv);    // cross-wave consumer (phase 1, after E)
        }
      }
    }
    // (barrier D removed: ctx_s/h_s phase-5 reads are same-wave, in-order LDS pipe)
    // phase 5: o4 = (h+ctx)@out_W + b; mu/std/pred; write outputs; advance pos
    {
      float o4v = 0.0f;
      if (k < 4) {
        const float* hp = &h_s[i*16];
        const float* cx = &ctx_s[i*16];
        float acc = sb_o[k];
        #pragma unroll
        for (int m = 0; m < 16; ++m) acc = fmaf(hp[m]+cx[m], sW_o[m*4+k], acc);
        o4v = acc;
      }
      float sc = __shfl_down(o4v, 2, 64);   // lane k<2 grabs o4[2+k]
      if (k < 2) {
        float mu = o4v;
        float scale = fminf(fmaxf(sc, -9.0f), 4.0f);
        float sd = __expf(scale);
        float pr = fmaf(sd, nz, mu);
        int o = (t*B_ + bi)*2 + k;
        out[o]          = pr;
        out[MU_OFF + o] = mu;
        out[SD_OFF + o] = sd;
        pos_s[i*2+k] += pr;
        prev_s[i*2+k] = pr;
        prev_bf[i*2+k] = f2bf1(pr);
      }
    }
    __syncthreads(); // E: pos_s/ctx_bf/prev_bf cross-wave for next step
  }
  (void)prev_s;
}

extern "C" void kernel_launch(void* const* d_in, const int* in_sizes, int n_in,
                              void* d_out, int out_size, void* d_ws, size_t ws_size,
                              hipStream_t stream) {
  (void)in_sizes; (void)n_in; (void)d_ws; (void)ws_size; (void)out_size;
  traj_ar_kernel<<<dim3(S_), dim3(256), 0, stream>>>(
      (const float*)d_in[0],  (const float*)d_in[1],  (const int*)d_in[2],   (const float*)d_in[3],
      (const float*)d_in[4],  (const float*)d_in[5],  (const float*)d_in[6], (const float*)d_in[7],
      (const float*)d_in[8],  (const float*)d_in[9],  (const float*)d_in[10],(const float*)d_in[11],
      (const float*)d_in[12], (const float*)d_in[13], (const float*)d_in[14],(const float*)d_in[15],
      (const float*)d_in[16], (const float*)d_in[17], (const float*)d_in[18],(const float*)d_in[19],
      (float*)d_out);
}